// Round 2
// baseline (7321.810 us; speedup 1.0000x reference)
//
#include <hip/hip_runtime.h>
#include <hip/hip_bf16.h>
#include <hip/hip_cooperative_groups.h>

namespace cg = cooperative_groups;

#define T_DIM 512
#define B_DIM 64
#define U_DIM 1024
#define G_DIM 4128
#define K_DIM 1024
#define CH 64
#define NCHUNK (T_DIM / CH)
#define NBLK 256

typedef __attribute__((ext_vector_type(8))) __bf16 bf16x8;
typedef __attribute__((ext_vector_type(4))) float floatx4;

// column permutation: p<32 -> masters (f:0..15, i:16..31)
// p>=32: p-32 = u*4+g  ->  original col 32 + g*1024 + u   (u = l*64+c)
__device__ __forceinline__ int orig_col(int p) {
  return (p < 32) ? p : (32 + ((p - 32) & 3) * 1024 + ((p - 32) >> 2));
}

// ---------- prep: fp32 [1024][4128] -> bf16 [4128][1024], permuted rows ----------
__global__ __launch_bounds__(256) void transpose_perm_kernel(
    const float* __restrict__ src, __bf16* __restrict__ dst) {
  int idx = blockIdx.x * 256 + threadIdx.x;  // 4128 * 64 threads
  int p = idx >> 6;
  int kc = (idx & 63) << 4;
  int oc = orig_col(p);
  const float* s = src + (size_t)kc * G_DIM + oc;
  __bf16* d = dst + (size_t)p * K_DIM + kc;
#pragma unroll
  for (int j = 0; j < 16; ++j) d[j] = (__bf16)s[(size_t)j * G_DIM];
}

// ---------- GEMM1 chunk: Zxc[tl][b][p] = x[b*512+t0+tl][:] @ Wt[p][:] + bias ----------
__global__ __launch_bounds__(256) void gemm1_kernel(
    const float* __restrict__ x, const __bf16* __restrict__ Wt,
    const float* __restrict__ bias, float* __restrict__ Zxc, int t0) {
  __shared__ __bf16 As[64 * 40];
  __shared__ __bf16 Bs[64 * 40];
  int tid = threadIdx.x;
  int wave = tid >> 6, lane = tid & 63;
  int quad = lane >> 4, ln = lane & 15;
  int b = blockIdx.x;
  int p0 = blockIdx.y * 64;

  int srow = tid >> 2, skc = (tid & 3) << 3;
  const float* ap = x + (size_t)(b * T_DIM + t0 + srow) * K_DIM + skc;
  __bf16* asw = As + srow * 40 + skc;
  bool bval = (p0 + srow) < G_DIM;
  const __bf16* bp = Wt + (size_t)(p0 + srow) * K_DIM + skc;
  __bf16* bsw = Bs + srow * 40 + skc;

  floatx4 acc[4];
#pragma unroll
  for (int n = 0; n < 4; ++n) acc[n] = {0.f, 0.f, 0.f, 0.f};

  const __bf16* afp = As + (wave * 16 + ln) * 40 + (quad << 3);

  for (int k0 = 0; k0 < K_DIM; k0 += 32) {
    __syncthreads();
    float4 a0 = *(const float4*)(ap + k0);
    float4 a1 = *(const float4*)(ap + k0 + 4);
    bf16x8 av;
    av[0] = (__bf16)a0.x; av[1] = (__bf16)a0.y; av[2] = (__bf16)a0.z; av[3] = (__bf16)a0.w;
    av[4] = (__bf16)a1.x; av[5] = (__bf16)a1.y; av[6] = (__bf16)a1.z; av[7] = (__bf16)a1.w;
    *(bf16x8*)asw = av;
    bf16x8 bv;
    if (bval) {
      bv = *(const bf16x8*)(bp + k0);
    } else {
#pragma unroll
      for (int j = 0; j < 8; ++j) bv[j] = (__bf16)0.0f;
    }
    *(bf16x8*)bsw = bv;
    __syncthreads();
    bf16x8 af = *(const bf16x8*)afp;
#pragma unroll
    for (int n = 0; n < 4; ++n) {
      bf16x8 bf = *(const bf16x8*)(Bs + (n * 16 + ln) * 40 + (quad << 3));
      acc[n] = __builtin_amdgcn_mfma_f32_16x16x32_bf16(af, bf, acc[n], 0, 0, 0);
    }
  }
  int tb = wave * 16 + quad * 4;
#pragma unroll
  for (int n = 0; n < 4; ++n) {
    int p = p0 + n * 16 + ln;
    if (p < G_DIM) {
      float bz = bias[orig_col(p)];
#pragma unroll
      for (int r = 0; r < 4; ++r) {
        int tl = tb + r;
        Zxc[((size_t)tl * B_DIM + b) * G_DIM + p] = acc[n][r] + bz;
      }
    }
  }
}

// ---------- persistent cooperative recurrence (one chunk of CH steps) ----------
// 256 blocks x 384 thr. block = (ub, bh): u in [ub*16,+16), b in [bh*16,+16).
// Per-group (64-block) flag barrier; h exchange via IC (sc0 sc1).
// When do_gemm: each block also computes its own next-chunk Zxc slice
// (16 batches x its 96 cols, one t-row per step), hidden in the sync slack:
//   waves 4-5 stage x row during pointwise; waves 1-4 do gate tiles and
//   wave 5 the 2 shared master tiles (only when ub == tl -> unique writer)
//   between flag publish and poll; wave 0 stays free to publish + poll.
#define SMH 1032  // tile row stride in bf16 (1024 + 8 pad)

__global__ __launch_bounds__(384, 2) void recur_kernel(
    const float* __restrict__ Zxc, const __bf16* __restrict__ Wrt,
    __bf16* __restrict__ hb, float* __restrict__ cws,
    unsigned* __restrict__ flags, float* __restrict__ out, int t0,
    const float* __restrict__ x, const __bf16* __restrict__ Wt,
    const float* __restrict__ bias, float* __restrict__ Zxn, int do_gemm) {
  __shared__ __bf16 hsm[16 * SMH];
  __shared__ __bf16 xsm[16 * SMH];
  __shared__ float zsm[16 * 97];

  int tid = threadIdx.x;
  int wave = tid >> 6, lane = tid & 63;
  int quad = lane >> 4, ln = lane & 15;
  int blk = blockIdx.x;
  int ub = blk >> 2, bh = blk & 3;
  int u0 = ub * 16, b0 = bh * 16;

  // B fragments (recurrent weights): wave's 16 output cols, K=1024, in regs
  int col = wave * 16 + ln;
  int p = (col < 32) ? col : (32 + u0 * 4 + (col - 32));
  bf16x8 breg[32];
  {
    const __bf16* wrp = Wrt + (size_t)p * K_DIM + (quad << 3);
#pragma unroll
    for (int kk = 0; kk < 32; ++kk) breg[kk] = *(const bf16x8*)(wrp + kk * 32);
  }

  // fused-gemm setup (gate tile col for waves 1..4; master bias for wave 5)
  int gt = (wave >= 1 && wave <= 4) ? (wave - 1) : 0;
  int p_g = 32 + u0 * 4 + gt * 16 + ln;
  float bz_g = bias[orig_col(p_g)];
  float bz_m0 = bias[ln];
  float bz_m1 = bias[16 + ln];

  // pointwise mapping (first 256 threads)
  int pb = tid >> 4, pu = tid & 15;
  int u = u0 + pu, gb = b0 + pb;
  int lev = u >> 6;
  float c_reg = (tid < 256) ? cws[gb * U_DIM + u] : 0.f;

  // z staging mapping (all 384 threads, 4 cols each)
  int zpb = tid / 24, zq = tid % 24;
  int cg4 = zq << 2;
  int pz = (cg4 < 32) ? cg4 : (32 + u0 * 4 + (cg4 - 32));
  float* zw = zsm + zpb * 97 + cg4;

  const char* ar = (const char*)hsm + ln * (SMH * 2) + (quad << 4);
  const char* axp = (const char*)xsm + ln * (SMH * 2) + (quad << 4);

  // prefetch z for tl = 0
  float4 zpre = *(const float4*)(Zxc + ((size_t)0 * B_DIM + (b0 + zpb)) * G_DIM + pz);

  for (int tl = 0; tl < CH; ++tl) {
    int t = t0 + tl;
    int cur = t & 1;
    // stage h tile [16 x 1024] bf16 -> LDS.
    // sc0 sc1 loads: bypass (possibly stale) L1/L2, read the coherence point.
    if (tid < 256) {
      const char* hsrc = (const char*)(hb + ((size_t)cur * B_DIM + b0) * U_DIM);
      bf16x8 hreg[8];
#pragma unroll
      for (int it = 0; it < 8; ++it) {
        asm volatile("global_load_dwordx4 %0, %1, off sc0 sc1"
                     : "=v"(hreg[it])
                     : "v"(hsrc + it * 4096 + tid * 16));
      }
      asm volatile("s_waitcnt vmcnt(0)" ::: "memory");
      __builtin_amdgcn_sched_barrier(0);
#pragma unroll
      for (int it = 0; it < 8; ++it) {
        int pos = it * 4096 + tid * 16;
        *(bf16x8*)((char*)hsm + (pos >> 11) * (SMH * 2) + (pos & 2047)) = hreg[it];
      }
    }
    // commit prefetched z
    zw[0] = zpre.x; zw[1] = zpre.y; zw[2] = zpre.z; zw[3] = zpre.w;
    __syncthreads();
    // z += h @ WrT : each wave one 16x16 tile over K=1024
    floatx4 acc = {0.f, 0.f, 0.f, 0.f};
#pragma unroll
    for (int kk = 0; kk < 32; ++kk) {
      bf16x8 a = *(const bf16x8*)(ar + kk * 64);
      acc = __builtin_amdgcn_mfma_f32_16x16x32_bf16(a, breg[kk], acc, 0, 0, 0);
    }
#pragma unroll
    for (int r = 0; r < 4; ++r) zsm[(quad * 4 + r) * 97 + col] += acc[r];
    __syncthreads();
    // prefetch z for next step (overlaps pointwise compute + store drain)
    if (tl + 1 < CH)
      zpre = *(const float4*)(Zxc + ((size_t)(tl + 1) * B_DIM + (b0 + zpb)) * G_DIM + pz);
    // pointwise ONLSTM update (waves 0-3) || x-row staging for fused gemm (waves 4-5)
    if (tid < 256) {
      const float* zrow = zsm + pb * 97;
      float zf[16], zi[16];
#pragma unroll
      for (int j = 0; j < 16; ++j) { zf[j] = zrow[j]; zi[j] = zrow[16 + j]; }
      float mf = zf[0], mi = zi[0];
#pragma unroll
      for (int j = 1; j < 16; ++j) { mf = fmaxf(mf, zf[j]); mi = fmaxf(mi, zi[j]); }
      float sf = 0.f, cf = 0.f, si = 0.f, ci = 0.f;
#pragma unroll
      for (int j = 0; j < 16; ++j) {
        float ef = __expf(zf[j] - mf);
        sf += ef; if (j <= lev) cf += ef;
        float ei = __expf(zi[j] - mi);
        si += ei; if (j >= lev) ci += ei;
      }
      float fm = cf / sf;   // l2r cumsoftmax (inclusive)
      float im = ci / si;   // r2l cumsoftmax (inclusive)
      float ov = fm * im;
      float g0 = zrow[32 + pu * 4 + 0];
      float g1 = zrow[32 + pu * 4 + 1];
      float g2 = zrow[32 + pu * 4 + 2];
      float g3 = zrow[32 + pu * 4 + 3];
      float fg = 1.f / (1.f + __expf(-g0));
      float ig = 1.f / (1.f + __expf(-g1));
      float og = 1.f / (1.f + __expf(-g2));
      float cin = 1.f - 2.f / (1.f + __expf(2.f * g3));
      c_reg = c_reg * (ov * fg + fm - ov) + cin * (ov * ig + im - ov);
      float hvout = og * (1.f - 2.f / (1.f + __expf(2.f * c_reg)));
      out[((size_t)gb * T_DIM + t) * U_DIM + u] = hvout;
      // h store: write-through to the coherence point (no wbl2 needed later)
      unsigned hd = (unsigned)__builtin_bit_cast(unsigned short, (__bf16)hvout);
      asm volatile("global_store_short %0, %1, off sc0 sc1"
                   :: "v"(hb + ((size_t)(cur ^ 1) * B_DIM + gb) * U_DIM + u),
                      "v"(hd)
                   : "memory");
    } else if (do_gemm) {
      // stage x[b0..b0+16][t + CH][:] -> bf16 xsm (next chunk, same t-row tl)
      int j = tid - 256;          // 0..127
      int r = j >> 3;             // row 0..15
      int kb = (j & 7) << 7;      // k base, 128 floats per thread
      const float* xp = x + ((size_t)(b0 + r) * T_DIM + (t + CH)) * K_DIM + kb;
      __bf16* xw = xsm + r * SMH + kb;
#pragma unroll
      for (int i = 0; i < 16; ++i) {
        float4 a0 = ((const float4*)xp)[2 * i];
        float4 a1 = ((const float4*)xp)[2 * i + 1];
        bf16x8 v;
        v[0] = (__bf16)a0.x; v[1] = (__bf16)a0.y; v[2] = (__bf16)a0.z; v[3] = (__bf16)a0.w;
        v[4] = (__bf16)a1.x; v[5] = (__bf16)a1.y; v[6] = (__bf16)a1.z; v[7] = (__bf16)a1.w;
        *(bf16x8*)(xw + 8 * i) = v;
      }
    }

    // release: drain sc1 h-stores (and x loads) before publishing the flag
    asm volatile("s_waitcnt vmcnt(0)" ::: "memory");
    __syncthreads();

    unsigned gen = (unsigned)(t + 1);
    if (tid == 0)
      __hip_atomic_store(&flags[blk], gen, __ATOMIC_RELAXED,
                         __HIP_MEMORY_SCOPE_AGENT);

    // fused gemm for next chunk's Zxc row tl, hidden in the sync slack
    if (do_gemm) {
      if (wave >= 1 && wave <= 4) {
        const __bf16* wxp = Wt + (size_t)p_g * K_DIM + (quad << 3);
        floatx4 ga = {0.f, 0.f, 0.f, 0.f};
#pragma unroll
        for (int kk = 0; kk < 32; ++kk) {
          bf16x8 a = *(const bf16x8*)(axp + kk * 64);
          bf16x8 bw = *(const bf16x8*)(wxp + kk * 32);
          ga = __builtin_amdgcn_mfma_f32_16x16x32_bf16(a, bw, ga, 0, 0, 0);
        }
#pragma unroll
        for (int r = 0; r < 4; ++r)
          Zxn[((size_t)tl * B_DIM + (b0 + quad * 4 + r)) * G_DIM + p_g] = ga[r] + bz_g;
      } else if (wave == 5 && ub == tl) {
        // shared master cols 0..31: exactly one writer block per group per row
#pragma unroll
        for (int m = 0; m < 2; ++m) {
          int pm = m * 16 + ln;
          const __bf16* wxp = Wt + (size_t)pm * K_DIM + (quad << 3);
          floatx4 ga = {0.f, 0.f, 0.f, 0.f};
#pragma unroll
          for (int kk = 0; kk < 32; ++kk) {
            bf16x8 a = *(const bf16x8*)(axp + kk * 64);
            bf16x8 bw = *(const bf16x8*)(wxp + kk * 32);
            ga = __builtin_amdgcn_mfma_f32_16x16x32_bf16(a, bw, ga, 0, 0, 0);
          }
          float bz = m ? bz_m1 : bz_m0;
#pragma unroll
          for (int r = 0; r < 4; ++r)
            Zxn[((size_t)tl * B_DIM + (b0 + quad * 4 + r)) * G_DIM + pm] = ga[r] + bz;
        }
      }
    }

    // ---- per-group (64-block) barrier poll (wave 0 only) ----
    if (tid < 64) {
      for (;;) {
        unsigned v = __hip_atomic_load(&flags[lane * 4 + bh], __ATOMIC_RELAXED,
                                       __HIP_MEMORY_SCOPE_AGENT);
        if (__all(v >= gen)) break;
      }
      // acquire side needs no cache maintenance: h reads bypass L1/L2 (sc0 sc1)
    }
    __syncthreads();
  }
  if (tid < 256) cws[gb * U_DIM + u] = c_reg;
}

extern "C" void kernel_launch(void* const* d_in, const int* in_sizes, int n_in,
                              void* d_out, int out_size, void* d_ws, size_t ws_size,
                              hipStream_t stream) {
  const float* x = (const float*)d_in[0];
  const float* W = (const float*)d_in[1];
  const float* Wr = (const float*)d_in[2];
  const float* bias = (const float*)d_in[3];
  float* out = (float*)d_out;

  const size_t ZXC_B = (size_t)CH * B_DIM * G_DIM * 4;    // 67,633,152
  const size_t WT_B = (size_t)G_DIM * K_DIM * 2;          // 8,454,144
  const size_t HB_B = (size_t)2 * B_DIM * U_DIM * 2;      // 262,144
  const size_t CW_B = (size_t)B_DIM * U_DIM * 4;          // 262,144
  const size_t FL_B = 4096;
  const size_t NEED1 = ZXC_B + 2 * WT_B + HB_B + CW_B + FL_B;   // ~85.1 MB
  const size_t NEED2 = NEED1 + ZXC_B;                           // ~152.7 MB
  if (ws_size < NEED1) return;
  const bool fused = (ws_size >= NEED2);

  char* ws = (char*)d_ws;
  float* ZxcA = (float*)ws;
  float* ZxcB = fused ? (float*)(ws + ZXC_B) : (float*)ws;
  char* rest = ws + (fused ? 2 : 1) * ZXC_B;
  __bf16* Wt = (__bf16*)rest;
  __bf16* Wrt = (__bf16*)(rest + WT_B);
  __bf16* hb = (__bf16*)(rest + 2 * WT_B);
  float* cws = (float*)(rest + 2 * WT_B + HB_B);
  unsigned* flags = (unsigned*)(rest + 2 * WT_B + HB_B + CW_B);

  hipMemsetAsync(hb, 0, HB_B, stream);
  hipMemsetAsync(cws, 0, CW_B, stream);
  hipMemsetAsync(flags, 0, FL_B, stream);
  transpose_perm_kernel<<<1032, 256, 0, stream>>>(W, Wt);
  transpose_perm_kernel<<<1032, 256, 0, stream>>>(Wr, Wrt);

  // chunk 0's input GEMM always runs standalone
  gemm1_kernel<<<dim3(64, 65), 256, 0, stream>>>(x, Wt, bias, ZxcA, 0);

  for (int c = 0; c < NCHUNK; ++c) {
    int t0 = c * CH;
    float* Zr = (c & 1) ? ZxcB : ZxcA;
    float* Zw = (c & 1) ? ZxcA : ZxcB;
    int dg = (fused && (c + 1 < NCHUNK)) ? 1 : 0;
    if (!fused && c > 0)
      gemm1_kernel<<<dim3(64, 65), 256, 0, stream>>>(x, Wt, bias, ZxcA, t0);
    void* args[] = {(void*)&Zr, (void*)&Wrt, (void*)&hb, (void*)&cws,
                    (void*)&flags, (void*)&out, (void*)&t0,
                    (void*)&x, (void*)&Wt, (void*)&bias, (void*)&Zw, (void*)&dg};
    hipLaunchCooperativeKernel((void*)recur_kernel, dim3(NBLK), dim3(384), args,
                               0, stream);
  }
}

// Round 4
// 6869.569 us; speedup vs baseline: 1.0658x; 1.0658x over previous
//
#include <hip/hip_runtime.h>
#include <hip/hip_bf16.h>

#define T_DIM 512
#define B_DIM 64
#define U_DIM 1024
#define G_DIM 4128
#define K_DIM 1024
#define CH 64
#define NCHUNK (T_DIM / CH)
#define NBLK 256
#define GBLK 256  // embedded-gemm blocks appended to the grid

typedef __attribute__((ext_vector_type(8))) __bf16 bf16x8;
typedef __attribute__((ext_vector_type(4))) float floatx4;

// column permutation: p<32 -> masters (f:0..15, i:16..31)
// p>=32: p-32 = u*4+g  ->  original col 32 + g*1024 + u   (u = l*64+c)
__device__ __forceinline__ int orig_col(int p) {
  return (p < 32) ? p : (32 + ((p - 32) & 3) * 1024 + ((p - 32) >> 2));
}

// ---------- prep: fp32 [1024][4128] -> bf16 [4128][1024], permuted rows ----------
__global__ __launch_bounds__(256) void transpose_perm_kernel(
    const float* __restrict__ src, __bf16* __restrict__ dst) {
  int idx = blockIdx.x * 256 + threadIdx.x;  // 4128 * 64 threads
  int p = idx >> 6;
  int kc = (idx & 63) << 4;
  int oc = orig_col(p);
  const float* s = src + (size_t)kc * G_DIM + oc;
  __bf16* d = dst + (size_t)p * K_DIM + kc;
#pragma unroll
  for (int j = 0; j < 16; ++j) d[j] = (__bf16)s[(size_t)j * G_DIM];
}

// ---------- GEMM1 chunk: Zxc[tl][b][p] = x[b*512+t0+tl][:] @ Wt[p][:] + bias ----------
__global__ __launch_bounds__(256) void gemm1_kernel(
    const float* __restrict__ x, const __bf16* __restrict__ Wt,
    const float* __restrict__ bias, float* __restrict__ Zxc, int t0) {
  __shared__ __bf16 As[64 * 40];
  __shared__ __bf16 Bs[64 * 40];
  int tid = threadIdx.x;
  int wave = tid >> 6, lane = tid & 63;
  int quad = lane >> 4, ln = lane & 15;
  int b = blockIdx.x;
  int p0 = blockIdx.y * 64;

  int srow = tid >> 2, skc = (tid & 3) << 3;
  const float* ap = x + (size_t)(b * T_DIM + t0 + srow) * K_DIM + skc;
  __bf16* asw = As + srow * 40 + skc;
  bool bval = (p0 + srow) < G_DIM;
  const __bf16* bp = Wt + (size_t)(p0 + srow) * K_DIM + skc;
  __bf16* bsw = Bs + srow * 40 + skc;

  floatx4 acc[4];
#pragma unroll
  for (int n = 0; n < 4; ++n) acc[n] = {0.f, 0.f, 0.f, 0.f};

  const __bf16* afp = As + (wave * 16 + ln) * 40 + (quad << 3);

  for (int k0 = 0; k0 < K_DIM; k0 += 32) {
    __syncthreads();
    float4 a0 = *(const float4*)(ap + k0);
    float4 a1 = *(const float4*)(ap + k0 + 4);
    bf16x8 av;
    av[0] = (__bf16)a0.x; av[1] = (__bf16)a0.y; av[2] = (__bf16)a0.z; av[3] = (__bf16)a0.w;
    av[4] = (__bf16)a1.x; av[5] = (__bf16)a1.y; av[6] = (__bf16)a1.z; av[7] = (__bf16)a1.w;
    *(bf16x8*)asw = av;
    bf16x8 bv;
    if (bval) {
      bv = *(const bf16x8*)(bp + k0);
    } else {
#pragma unroll
      for (int j = 0; j < 8; ++j) bv[j] = (__bf16)0.0f;
    }
    *(bf16x8*)bsw = bv;
    __syncthreads();
    bf16x8 af = *(const bf16x8*)afp;
#pragma unroll
    for (int n = 0; n < 4; ++n) {
      bf16x8 bf = *(const bf16x8*)(Bs + (n * 16 + ln) * 40 + (quad << 3));
      acc[n] = __builtin_amdgcn_mfma_f32_16x16x32_bf16(af, bf, acc[n], 0, 0, 0);
    }
  }
  int tb = wave * 16 + quad * 4;
#pragma unroll
  for (int n = 0; n < 4; ++n) {
    int p = p0 + n * 16 + ln;
    if (p < G_DIM) {
      float bz = bias[orig_col(p)];
#pragma unroll
      for (int r = 0; r < 4; ++r) {
        int tl = tb + r;
        Zxc[((size_t)tl * B_DIM + b) * G_DIM + p] = acc[n][r] + bz;
      }
    }
  }
}

// ---------- persistent recurrence + co-scheduled next-chunk GEMM ----------
// PLAIN launch, 512 blocks x 384 thr (NOT cooperative — no grid.sync used).
//   blocks 0..255  : recurrence. block = (ub, bh): u in [ub*16,+16), b in [bh*16,+16).
//                    Per-group (64-block) flag barrier; h exchange via IC (sc0 sc1).
//                    Deadlock-free: worst-case capacity is 256 blocks (1/CU), and
//                    gemm blocks never wait on recur -> they drain and free slots.
//   blocks 256..511: when do_gemm, persistent job loop over the NEXT chunk's input
//                    GEMM tiles (identical LDS-tiled structure to gemm1_kernel).
//                    All 6 waves stay alive for barriers; waves 4-5 idle at them.
#define SMH 1032  // h-tile row stride in bf16 (1024 + 8 pad)

__global__ __launch_bounds__(384, 3) void recur_kernel(
    const float* __restrict__ Zxc, const __bf16* __restrict__ Wrt,
    __bf16* __restrict__ hb, float* __restrict__ cws,
    unsigned* __restrict__ flags, float* __restrict__ out, int t0,
    const float* __restrict__ x, const __bf16* __restrict__ Wt,
    const float* __restrict__ bias, float* __restrict__ Zxn, int do_gemm) {
  __shared__ __bf16 hsm[16 * SMH];
  __shared__ float zsm[16 * 97];
  __shared__ __bf16 As[64 * 40];
  __shared__ __bf16 Bs[64 * 40];

  int tid = threadIdx.x;
  int wave = tid >> 6, lane = tid & 63;
  int quad = lane >> 4, ln = lane & 15;
  int blk = blockIdx.x;

  if (blk >= NBLK) {
    // ================= embedded next-chunk input GEMM =================
    if (!do_gemm) return;  // whole block exits together
    int gblk = blk - NBLK;
    int t0n = t0 + CH;
    int srow = tid >> 2, skc = (tid & 3) << 3;  // meaningful for tid<256
    for (int job = gblk; job < 64 * 65; job += GBLK) {
      int b = job & 63;
      int p0 = (job >> 6) << 6;
      const float* ap = x + (size_t)(b * T_DIM + t0n + srow) * K_DIM + skc;
      __bf16* asw = As + srow * 40 + skc;
      bool bval = (p0 + srow) < G_DIM;
      const __bf16* bp = Wt + (size_t)(p0 + srow) * K_DIM + skc;
      __bf16* bsw = Bs + srow * 40 + skc;

      floatx4 acc[4];
#pragma unroll
      for (int n = 0; n < 4; ++n) acc[n] = {0.f, 0.f, 0.f, 0.f};
      const __bf16* afp = As + (wave * 16 + ln) * 40 + (quad << 3);

      for (int k0 = 0; k0 < K_DIM; k0 += 32) {
        __syncthreads();  // ALL 384 threads
        if (tid < 256) {
          float4 a0 = *(const float4*)(ap + k0);
          float4 a1 = *(const float4*)(ap + k0 + 4);
          bf16x8 av;
          av[0] = (__bf16)a0.x; av[1] = (__bf16)a0.y; av[2] = (__bf16)a0.z; av[3] = (__bf16)a0.w;
          av[4] = (__bf16)a1.x; av[5] = (__bf16)a1.y; av[6] = (__bf16)a1.z; av[7] = (__bf16)a1.w;
          *(bf16x8*)asw = av;
          bf16x8 bv;
          if (bval) {
            bv = *(const bf16x8*)(bp + k0);
          } else {
#pragma unroll
            for (int j = 0; j < 8; ++j) bv[j] = (__bf16)0.0f;
          }
          *(bf16x8*)bsw = bv;
        }
        __syncthreads();  // ALL 384 threads
        if (tid < 256) {
          bf16x8 af = *(const bf16x8*)afp;
#pragma unroll
          for (int n = 0; n < 4; ++n) {
            bf16x8 bf = *(const bf16x8*)(Bs + (n * 16 + ln) * 40 + (quad << 3));
            acc[n] = __builtin_amdgcn_mfma_f32_16x16x32_bf16(af, bf, acc[n], 0, 0, 0);
          }
        }
      }
      if (tid < 256) {
        int tb = wave * 16 + quad * 4;
#pragma unroll
        for (int n = 0; n < 4; ++n) {
          int p = p0 + n * 16 + ln;
          if (p < G_DIM) {
            float bz = bias[orig_col(p)];
#pragma unroll
            for (int r = 0; r < 4; ++r) {
              int tl = tb + r;
              Zxn[((size_t)tl * B_DIM + b) * G_DIM + p] = acc[n][r] + bz;
            }
          }
        }
      }
    }
    return;
  }

  // ================= recurrence =================
  int ub = blk >> 2, bh = blk & 3;
  int u0 = ub * 16, b0 = bh * 16;

  // B fragments (recurrent weights): wave's 16 output cols, K=1024, in regs
  int col = wave * 16 + ln;
  int p = (col < 32) ? col : (32 + u0 * 4 + (col - 32));
  bf16x8 breg[32];
  {
    const __bf16* wrp = Wrt + (size_t)p * K_DIM + (quad << 3);
#pragma unroll
    for (int kk = 0; kk < 32; ++kk) breg[kk] = *(const bf16x8*)(wrp + kk * 32);
  }

  // pointwise mapping (first 256 threads)
  int pb = tid >> 4, pu = tid & 15;
  int u = u0 + pu, gb = b0 + pb;
  int lev = u >> 6;
  float c_reg = (tid < 256) ? cws[gb * U_DIM + u] : 0.f;

  // z staging mapping (all 384 threads, 4 cols each)
  int zpb = tid / 24, zq = tid % 24;
  int cg4 = zq << 2;
  int pz = (cg4 < 32) ? cg4 : (32 + u0 * 4 + (cg4 - 32));
  float* zw = zsm + zpb * 97 + cg4;

  const char* ar = (const char*)hsm + ln * (SMH * 2) + (quad << 4);

  // prefetch z for tl = 0
  float4 zpre = *(const float4*)(Zxc + ((size_t)0 * B_DIM + (b0 + zpb)) * G_DIM + pz);

  for (int tl = 0; tl < CH; ++tl) {
    int t = t0 + tl;
    int cur = t & 1;
    // stage h tile [16 x 1024] bf16 -> LDS.
    // sc0 sc1 loads: bypass (possibly stale) L1/L2, read the coherence point.
    if (tid < 256) {
      const char* hsrc = (const char*)(hb + ((size_t)cur * B_DIM + b0) * U_DIM);
      bf16x8 hreg[8];
#pragma unroll
      for (int it = 0; it < 8; ++it) {
        asm volatile("global_load_dwordx4 %0, %1, off sc0 sc1"
                     : "=v"(hreg[it])
                     : "v"(hsrc + it * 4096 + tid * 16));
      }
      asm volatile("s_waitcnt vmcnt(0)" ::: "memory");
      __builtin_amdgcn_sched_barrier(0);
#pragma unroll
      for (int it = 0; it < 8; ++it) {
        int pos = it * 4096 + tid * 16;
        *(bf16x8*)((char*)hsm + (pos >> 11) * (SMH * 2) + (pos & 2047)) = hreg[it];
      }
    }
    // commit prefetched z
    zw[0] = zpre.x; zw[1] = zpre.y; zw[2] = zpre.z; zw[3] = zpre.w;
    __syncthreads();
    // z += h @ WrT : each wave one 16x16 tile over K=1024
    floatx4 acc = {0.f, 0.f, 0.f, 0.f};
#pragma unroll
    for (int kk = 0; kk < 32; ++kk) {
      bf16x8 a = *(const bf16x8*)(ar + kk * 64);
      acc = __builtin_amdgcn_mfma_f32_16x16x32_bf16(a, breg[kk], acc, 0, 0, 0);
    }
#pragma unroll
    for (int r = 0; r < 4; ++r) zsm[(quad * 4 + r) * 97 + col] += acc[r];
    __syncthreads();
    // prefetch z for next step (overlaps pointwise compute + store drain)
    if (tl + 1 < CH)
      zpre = *(const float4*)(Zxc + ((size_t)(tl + 1) * B_DIM + (b0 + zpb)) * G_DIM + pz);
    // pointwise ONLSTM update
    if (tid < 256) {
      const float* zrow = zsm + pb * 97;
      float zf[16], zi[16];
#pragma unroll
      for (int j = 0; j < 16; ++j) { zf[j] = zrow[j]; zi[j] = zrow[16 + j]; }
      float mf = zf[0], mi = zi[0];
#pragma unroll
      for (int j = 1; j < 16; ++j) { mf = fmaxf(mf, zf[j]); mi = fmaxf(mi, zi[j]); }
      float sf = 0.f, cf = 0.f, si = 0.f, ci = 0.f;
#pragma unroll
      for (int j = 0; j < 16; ++j) {
        float ef = __expf(zf[j] - mf);
        sf += ef; if (j <= lev) cf += ef;
        float ei = __expf(zi[j] - mi);
        si += ei; if (j >= lev) ci += ei;
      }
      float fm = cf / sf;   // l2r cumsoftmax (inclusive)
      float im = ci / si;   // r2l cumsoftmax (inclusive)
      float ov = fm * im;
      float g0 = zrow[32 + pu * 4 + 0];
      float g1 = zrow[32 + pu * 4 + 1];
      float g2 = zrow[32 + pu * 4 + 2];
      float g3 = zrow[32 + pu * 4 + 3];
      float fg = 1.f / (1.f + __expf(-g0));
      float ig = 1.f / (1.f + __expf(-g1));
      float og = 1.f / (1.f + __expf(-g2));
      float cin = 1.f - 2.f / (1.f + __expf(2.f * g3));
      c_reg = c_reg * (ov * fg + fm - ov) + cin * (ov * ig + im - ov);
      float hvout = og * (1.f - 2.f / (1.f + __expf(2.f * c_reg)));
      out[((size_t)gb * T_DIM + t) * U_DIM + u] = hvout;
      // h store: write-through to the coherence point (no wbl2 needed later)
      unsigned hd = (unsigned)__builtin_bit_cast(unsigned short, (__bf16)hvout);
      asm volatile("global_store_short %0, %1, off sc0 sc1"
                   :: "v"(hb + ((size_t)(cur ^ 1) * B_DIM + gb) * U_DIM + u),
                      "v"(hd)
                   : "memory");
    }

    // ---- per-group (64-block) barrier, gen = t+1 (monotonic across chunks) ----
    // release: drain sc1 h-stores to IC before publishing the flag
    asm volatile("s_waitcnt vmcnt(0)" ::: "memory");
    __syncthreads();
    if (tid < 64) {
      unsigned gen = (unsigned)(t + 1);
      if (tid == 0)
        __hip_atomic_store(&flags[blk], gen, __ATOMIC_RELAXED,
                           __HIP_MEMORY_SCOPE_AGENT);
      for (;;) {
        unsigned v = __hip_atomic_load(&flags[lane * 4 + bh], __ATOMIC_RELAXED,
                                       __HIP_MEMORY_SCOPE_AGENT);
        if (__all(v >= gen)) break;
      }
      // acquire side needs no cache maintenance: h reads bypass L1/L2 (sc0 sc1)
    }
    __syncthreads();
  }
  if (tid < 256) cws[gb * U_DIM + u] = c_reg;
}

extern "C" void kernel_launch(void* const* d_in, const int* in_sizes, int n_in,
                              void* d_out, int out_size, void* d_ws, size_t ws_size,
                              hipStream_t stream) {
  const float* x = (const float*)d_in[0];
  const float* W = (const float*)d_in[1];
  const float* Wr = (const float*)d_in[2];
  const float* bias = (const float*)d_in[3];
  float* out = (float*)d_out;

  const size_t ZXC_B = (size_t)CH * B_DIM * G_DIM * 4;    // 67,633,152
  const size_t WT_B = (size_t)G_DIM * K_DIM * 2;          // 8,454,144
  const size_t HB_B = (size_t)2 * B_DIM * U_DIM * 2;      // 262,144
  const size_t CW_B = (size_t)B_DIM * U_DIM * 4;          // 262,144
  const size_t FL_B = 4096;
  const size_t NEED1 = ZXC_B + 2 * WT_B + HB_B + CW_B + FL_B;   // ~85.1 MB
  const size_t NEED2 = NEED1 + ZXC_B;                           // ~152.7 MB
  if (ws_size < NEED1) return;
  const bool fused = (ws_size >= NEED2);

  char* ws = (char*)d_ws;
  float* ZxcA = (float*)ws;
  float* ZxcB = fused ? (float*)(ws + ZXC_B) : (float*)ws;
  char* rest = ws + (fused ? 2 : 1) * ZXC_B;
  __bf16* Wt = (__bf16*)rest;
  __bf16* Wrt = (__bf16*)(rest + WT_B);
  __bf16* hb = (__bf16*)(rest + 2 * WT_B);
  float* cws = (float*)(rest + 2 * WT_B + HB_B);
  unsigned* flags = (unsigned*)(rest + 2 * WT_B + HB_B + CW_B);

  hipMemsetAsync(hb, 0, HB_B, stream);
  hipMemsetAsync(cws, 0, CW_B, stream);
  hipMemsetAsync(flags, 0, FL_B, stream);
  transpose_perm_kernel<<<1032, 256, 0, stream>>>(W, Wt);
  transpose_perm_kernel<<<1032, 256, 0, stream>>>(Wr, Wrt);

  // chunk 0's input GEMM always runs standalone
  gemm1_kernel<<<dim3(64, 65), 256, 0, stream>>>(x, Wt, bias, ZxcA, 0);

  for (int c = 0; c < NCHUNK; ++c) {
    int t0 = c * CH;
    float* Zr = (c & 1) ? ZxcB : ZxcA;
    float* Zw = (c & 1) ? ZxcA : ZxcB;
    int dg = (fused && (c + 1 < NCHUNK)) ? 1 : 0;
    if (!fused && c > 0)
      gemm1_kernel<<<dim3(64, 65), 256, 0, stream>>>(x, Wt, bias, ZxcA, t0);
    recur_kernel<<<dim3(NBLK + GBLK), dim3(384), 0, stream>>>(
        Zr, Wrt, hb, cws, flags, out, t0, x, Wt, bias, Zw, dg);
  }
}

// Round 5
// 3467.211 us; speedup vs baseline: 2.1117x; 1.9813x over previous
//
#include <hip/hip_runtime.h>
#include <hip/hip_bf16.h>

#define T_DIM 512
#define B_DIM 64
#define U_DIM 1024
#define G_DIM 4128
#define K_DIM 1024
#define CH 64
#define NCHUNK (T_DIM / CH)
#define NBLK 256

typedef __attribute__((ext_vector_type(8))) __bf16 bf16x8;
typedef __attribute__((ext_vector_type(4))) float floatx4;

// column permutation: p<32 -> masters (f:0..15, i:16..31)
// p>=32: p-32 = u*4+g  ->  original col 32 + g*1024 + u   (u = l*64+c)
__device__ __forceinline__ int orig_col(int p) {
  return (p < 32) ? p : (32 + ((p - 32) & 3) * 1024 + ((p - 32) >> 2));
}

// ---------- prep: fp32 [1024][4128] -> bf16 [4128][1024], permuted rows ----------
__global__ __launch_bounds__(256) void transpose_perm_kernel(
    const float* __restrict__ src, __bf16* __restrict__ dst) {
  int idx = blockIdx.x * 256 + threadIdx.x;  // 4128 * 64 threads
  int p = idx >> 6;
  int kc = (idx & 63) << 4;
  int oc = orig_col(p);
  const float* s = src + (size_t)kc * G_DIM + oc;
  __bf16* d = dst + (size_t)p * K_DIM + kc;
#pragma unroll
  for (int j = 0; j < 16; ++j) d[j] = (__bf16)s[(size_t)j * G_DIM];
}

// ---------- prep: permuted bias ----------
__global__ __launch_bounds__(256) void biasperm_kernel(
    const float* __restrict__ bias, float* __restrict__ biasP) {
  int p = blockIdx.x * 256 + threadIdx.x;
  if (p < G_DIM) biasP[p] = bias[orig_col(p)];
}

// ---------- prep: x [B][T][K] fp32 -> xt [(t*64+b)][K] bf16 ----------
__global__ __launch_bounds__(256) void xcast_kernel(
    const float* __restrict__ x, __bf16* __restrict__ xt) {
  int idx = blockIdx.x * 256 + threadIdx.x;  // 512*64*128
  int kc = (idx & 127) << 3;
  int row = idx >> 7;  // t*64+b
  int t = row >> 6, b = row & 63;
  const float* s = x + ((size_t)b * T_DIM + t) * K_DIM + kc;
  float4 f0 = *(const float4*)s;
  float4 f1 = *(const float4*)(s + 4);
  bf16x8 v;
  v[0] = (__bf16)f0.x; v[1] = (__bf16)f0.y; v[2] = (__bf16)f0.z; v[3] = (__bf16)f0.w;
  v[4] = (__bf16)f1.x; v[5] = (__bf16)f1.y; v[6] = (__bf16)f1.z; v[7] = (__bf16)f1.w;
  *(bf16x8*)(xt + (size_t)row * K_DIM + kc) = v;
}

// ---------- fallback GEMM1 (fp32 x, 64x64 tiles) ----------
__global__ __launch_bounds__(256) void gemm1_kernel(
    const float* __restrict__ x, const __bf16* __restrict__ Wt,
    const float* __restrict__ bias, float* __restrict__ Zxc, int t0) {
  __shared__ __bf16 As[64 * 40];
  __shared__ __bf16 Bs[64 * 40];
  int tid = threadIdx.x;
  int wave = tid >> 6, lane = tid & 63;
  int quad = lane >> 4, ln = lane & 15;
  int b = blockIdx.x;
  int p0 = blockIdx.y * 64;

  int srow = tid >> 2, skc = (tid & 3) << 3;
  const float* ap = x + (size_t)(b * T_DIM + t0 + srow) * K_DIM + skc;
  __bf16* asw = As + srow * 40 + skc;
  bool bval = (p0 + srow) < G_DIM;
  const __bf16* bp = Wt + (size_t)(p0 + srow) * K_DIM + skc;
  __bf16* bsw = Bs + srow * 40 + skc;

  floatx4 acc[4];
#pragma unroll
  for (int n = 0; n < 4; ++n) acc[n] = {0.f, 0.f, 0.f, 0.f};
  const __bf16* afp = As + (wave * 16 + ln) * 40 + (quad << 3);

  for (int k0 = 0; k0 < K_DIM; k0 += 32) {
    __syncthreads();
    float4 a0 = *(const float4*)(ap + k0);
    float4 a1 = *(const float4*)(ap + k0 + 4);
    bf16x8 av;
    av[0] = (__bf16)a0.x; av[1] = (__bf16)a0.y; av[2] = (__bf16)a0.z; av[3] = (__bf16)a0.w;
    av[4] = (__bf16)a1.x; av[5] = (__bf16)a1.y; av[6] = (__bf16)a1.z; av[7] = (__bf16)a1.w;
    *(bf16x8*)asw = av;
    bf16x8 bv;
    if (bval) {
      bv = *(const bf16x8*)(bp + k0);
    } else {
#pragma unroll
      for (int j = 0; j < 8; ++j) bv[j] = (__bf16)0.0f;
    }
    *(bf16x8*)bsw = bv;
    __syncthreads();
    bf16x8 af = *(const bf16x8*)afp;
#pragma unroll
    for (int n = 0; n < 4; ++n) {
      bf16x8 bf = *(const bf16x8*)(Bs + (n * 16 + ln) * 40 + (quad << 3));
      acc[n] = __builtin_amdgcn_mfma_f32_16x16x32_bf16(af, bf, acc[n], 0, 0, 0);
    }
  }
  int tb = wave * 16 + quad * 4;
#pragma unroll
  for (int n = 0; n < 4; ++n) {
    int p = p0 + n * 16 + ln;
    if (p < G_DIM) {
      float bz = bias[orig_col(p)];
#pragma unroll
      for (int r = 0; r < 4; ++r)
        Zxc[((size_t)(tb + r) * B_DIM + b) * G_DIM + p] = acc[n][r] + bz;
    }
  }
}

// ---------- fast GEMM1: 128x128 tile, BK=64, 8 waves, XOR-swizzled LDS ----------
// A = xt chunk [4096 rows (tl*64+b)][1024] bf16 (contiguous), B = Wt [4128][1024].
// Zxc row (tl*64+b) == A row -> direct mapping.
__global__ __launch_bounds__(512, 4) void gemm1f_kernel(
    const __bf16* __restrict__ xtc, const __bf16* __restrict__ Wt,
    const float* __restrict__ biasP, float* __restrict__ Zxc) {
  __shared__ __bf16 As[128 * 64];
  __shared__ __bf16 Bs[128 * 64];
  int tid = threadIdx.x;
  int lane = tid & 63;
  int wave = tid >> 6;
  int wr = wave >> 2, wc = wave & 3;   // wave tile: rows [wr*64,+64), cols [wc*32,+32)
  int quad = lane >> 4, ln = lane & 15;
  int m0 = blockIdx.x * 128;
  int p0 = blockIdx.y * 128;

  // staging: thread -> row (tid>>2), 32B at byte-cols (tid&3)*32
  int srow = tid >> 2;
  int scolb = (tid & 3) << 5;  // byte col 0,32,64,96
  const __bf16* ga = xtc + (size_t)(m0 + srow) * K_DIM + (scolb >> 1);
  bool bval = (p0 + srow) < G_DIM;
  const __bf16* gb = Wt + (size_t)(p0 + srow) * K_DIM + (scolb >> 1);
  int sw = (srow & 7) << 4;
  int w0 = srow * 128 + (scolb ^ sw);
  int w1 = srow * 128 + ((scolb + 16) ^ sw);

  floatx4 acc[4][2];
#pragma unroll
  for (int mf = 0; mf < 4; ++mf)
#pragma unroll
    for (int nf = 0; nf < 2; ++nf) acc[mf][nf] = {0.f, 0.f, 0.f, 0.f};

  bf16x8 a0 = *(const bf16x8*)ga, a1 = *(const bf16x8*)(ga + 8);
  bf16x8 b0, b1;
  if (bval) {
    b0 = *(const bf16x8*)gb; b1 = *(const bf16x8*)(gb + 8);
  } else {
#pragma unroll
    for (int j = 0; j < 8; ++j) { b0[j] = (__bf16)0.0f; b1[j] = (__bf16)0.0f; }
  }

  int arow0 = wr * 64 + ln;
  int brow0 = wc * 32 + ln;

  for (int k0 = 0; k0 < K_DIM; k0 += 64) {
    __syncthreads();
    *(bf16x8*)((char*)As + w0) = a0; *(bf16x8*)((char*)As + w1) = a1;
    *(bf16x8*)((char*)Bs + w0) = b0; *(bf16x8*)((char*)Bs + w1) = b1;
    __syncthreads();
    if (k0 + 64 < K_DIM) {
      a0 = *(const bf16x8*)(ga + k0 + 64); a1 = *(const bf16x8*)(ga + k0 + 72);
      if (bval) {
        b0 = *(const bf16x8*)(gb + k0 + 64); b1 = *(const bf16x8*)(gb + k0 + 72);
      }
    }
#pragma unroll
    for (int kk = 0; kk < 2; ++kk) {
      int kb = kk * 64 + quad * 16;  // byte offset of lane's 8 bf16 in K
      bf16x8 bfr[2];
#pragma unroll
      for (int nf = 0; nf < 2; ++nf) {
        int row = brow0 + nf * 16;
        bfr[nf] = *(const bf16x8*)((char*)Bs + row * 128 + (kb ^ ((row & 7) << 4)));
      }
#pragma unroll
      for (int mf = 0; mf < 4; ++mf) {
        int row = arow0 + mf * 16;
        bf16x8 af = *(const bf16x8*)((char*)As + row * 128 + (kb ^ ((row & 7) << 4)));
#pragma unroll
        for (int nf = 0; nf < 2; ++nf)
          acc[mf][nf] = __builtin_amdgcn_mfma_f32_16x16x32_bf16(af, bfr[nf], acc[mf][nf], 0, 0, 0);
      }
    }
  }
#pragma unroll
  for (int nf = 0; nf < 2; ++nf) {
    int pp = p0 + wc * 32 + nf * 16 + ln;
    if (pp < G_DIM) {
      float bz = biasP[pp];
#pragma unroll
      for (int mf = 0; mf < 4; ++mf) {
        int mrow = m0 + wr * 64 + mf * 16 + quad * 4;
#pragma unroll
        for (int r = 0; r < 4; ++r)
          Zxc[(size_t)(mrow + r) * G_DIM + pp] = acc[mf][nf][r] + bz;
      }
    }
  }
}

// ---------- persistent recurrence (one chunk of CH steps) ----------
// 256 blocks x 384 thr, plain launch. block = (ub, bh): u in [ub*16,+16), b in [bh*16,+16).
// Per-group (64-block) flag barrier; h exchange via IC (sc0 sc1 write-through).
// Release waits ONLY the h stores; out-store + Zx prefetch happen after publish.
#define SMH 1032  // h-tile row stride in bf16 (1024 + 8 pad)

__global__ __launch_bounds__(384, 2) void recur_kernel(
    const float* __restrict__ Zxc, const __bf16* __restrict__ Wrt,
    __bf16* __restrict__ hb, float* __restrict__ cws,
    unsigned* __restrict__ flags, float* __restrict__ out, int t0) {
  __shared__ __bf16 hsm[16 * SMH];
  __shared__ float zsm[16 * 97];

  int tid = threadIdx.x;
  int wave = tid >> 6, lane = tid & 63;
  int quad = lane >> 4, ln = lane & 15;
  int blk = blockIdx.x;
  int ub = blk >> 2, bh = blk & 3;
  int u0 = ub * 16, b0 = bh * 16;

  // B fragments (recurrent weights): wave's 16 output cols, K=1024, in regs
  int col = wave * 16 + ln;
  int p = (col < 32) ? col : (32 + u0 * 4 + (col - 32));
  bf16x8 breg[32];
  {
    const __bf16* wrp = Wrt + (size_t)p * K_DIM + (quad << 3);
#pragma unroll
    for (int kk = 0; kk < 32; ++kk) breg[kk] = *(const bf16x8*)(wrp + kk * 32);
  }

  // pointwise mapping (first 256 threads)
  int pb = tid >> 4, pu = tid & 15;
  int u = u0 + pu, gb = b0 + pb;
  int lev = u >> 6;
  float c_reg = (tid < 256) ? cws[gb * U_DIM + u] : 0.f;

  // z staging mapping (all 384 threads, 4 cols each)
  int zpb = tid / 24, zq = tid % 24;
  int cg4 = zq << 2;
  int pz = (cg4 < 32) ? cg4 : (32 + u0 * 4 + (cg4 - 32));
  float* zw = zsm + zpb * 97 + cg4;

  const char* ar = (const char*)hsm + ln * (SMH * 2) + (quad << 4);

  // prefetch z for tl = 0
  float4 zpre = *(const float4*)(Zxc + ((size_t)0 * B_DIM + (b0 + zpb)) * G_DIM + pz);

  for (int tl = 0; tl < CH; ++tl) {
    int t = t0 + tl;
    int cur = t & 1;
    // stage h tile [16 x 1024] bf16 -> LDS (sc0 sc1: read the coherence point)
    if (tid < 256) {
      const char* hsrc = (const char*)(hb + ((size_t)cur * B_DIM + b0) * U_DIM);
      bf16x8 hreg[8];
#pragma unroll
      for (int it = 0; it < 8; ++it) {
        asm volatile("global_load_dwordx4 %0, %1, off sc0 sc1"
                     : "=v"(hreg[it])
                     : "v"(hsrc + it * 4096 + tid * 16));
      }
      asm volatile("s_waitcnt vmcnt(0)" ::: "memory");
      __builtin_amdgcn_sched_barrier(0);
#pragma unroll
      for (int it = 0; it < 8; ++it) {
        int pos = it * 4096 + tid * 16;
        *(bf16x8*)((char*)hsm + (pos >> 11) * (SMH * 2) + (pos & 2047)) = hreg[it];
      }
    }
    // commit prefetched z
    zw[0] = zpre.x; zw[1] = zpre.y; zw[2] = zpre.z; zw[3] = zpre.w;
    __syncthreads();
    // z += h @ WrT : each wave one 16x16 tile over K=1024 (2 interleaved chains)
    floatx4 acc0 = {0.f, 0.f, 0.f, 0.f}, acc1 = {0.f, 0.f, 0.f, 0.f};
#pragma unroll
    for (int kk = 0; kk < 32; kk += 2) {
      bf16x8 ae = *(const bf16x8*)(ar + kk * 64);
      bf16x8 ao = *(const bf16x8*)(ar + kk * 64 + 64);
      acc0 = __builtin_amdgcn_mfma_f32_16x16x32_bf16(ae, breg[kk], acc0, 0, 0, 0);
      acc1 = __builtin_amdgcn_mfma_f32_16x16x32_bf16(ao, breg[kk + 1], acc1, 0, 0, 0);
    }
#pragma unroll
    for (int r = 0; r < 4; ++r) zsm[(quad * 4 + r) * 97 + col] += acc0[r] + acc1[r];
    __syncthreads();
    // pointwise ONLSTM update — h store FIRST (critical path), out deferred
    float hv_keep = 0.f;
    if (tid < 256) {
      const float* zrow = zsm + pb * 97;
      float zf[16], zi[16];
#pragma unroll
      for (int j = 0; j < 16; ++j) { zf[j] = zrow[j]; zi[j] = zrow[16 + j]; }
      float mf = zf[0], mi = zi[0];
#pragma unroll
      for (int j = 1; j < 16; ++j) { mf = fmaxf(mf, zf[j]); mi = fmaxf(mi, zi[j]); }
      float sf = 0.f, cf = 0.f, si = 0.f, ci = 0.f;
#pragma unroll
      for (int j = 0; j < 16; ++j) {
        float ef = __expf(zf[j] - mf);
        sf += ef; if (j <= lev) cf += ef;
        float ei = __expf(zi[j] - mi);
        si += ei; if (j >= lev) ci += ei;
      }
      float fm = cf / sf;   // l2r cumsoftmax (inclusive)
      float im = ci / si;   // r2l cumsoftmax (inclusive)
      float ov = fm * im;
      float g0 = zrow[32 + pu * 4 + 0];
      float g1 = zrow[32 + pu * 4 + 1];
      float g2 = zrow[32 + pu * 4 + 2];
      float g3 = zrow[32 + pu * 4 + 3];
      float fg = 1.f / (1.f + __expf(-g0));
      float ig = 1.f / (1.f + __expf(-g1));
      float og = 1.f / (1.f + __expf(-g2));
      float cin = 1.f - 2.f / (1.f + __expf(2.f * g3));
      c_reg = c_reg * (ov * fg + fm - ov) + cin * (ov * ig + im - ov);
      hv_keep = og * (1.f - 2.f / (1.f + __expf(2.f * c_reg)));
      // h store: write-through to the coherence point
      unsigned hd = (unsigned)__builtin_bit_cast(unsigned short, (__bf16)hv_keep);
      asm volatile("global_store_short %0, %1, off sc0 sc1"
                   :: "v"(hb + ((size_t)(cur ^ 1) * B_DIM + gb) * U_DIM + u),
                      "v"(hd)
                   : "memory");
    }
    // release: drain h stores only, then publish
    asm volatile("s_waitcnt vmcnt(0)" ::: "memory");
    __syncthreads();
    unsigned gen = (unsigned)(t + 1);
    if (tid == 0)
      __hip_atomic_store(&flags[blk], gen, __ATOMIC_RELAXED,
                         __HIP_MEMORY_SCOPE_AGENT);
    // off-critical-path work, hidden under the poll:
    if (tid < 256)
      out[((size_t)gb * T_DIM + t) * U_DIM + u] = hv_keep;
    if (tl + 1 < CH)
      zpre = *(const float4*)(Zxc + ((size_t)(tl + 1) * B_DIM + (b0 + zpb)) * G_DIM + pz);
    if (tid < 64) {
      for (;;) {
        unsigned v = __hip_atomic_load(&flags[lane * 4 + bh], __ATOMIC_RELAXED,
                                       __HIP_MEMORY_SCOPE_AGENT);
        if (__all(v >= gen)) break;
      }
      // acquire side needs no cache maintenance: h reads bypass L1/L2 (sc0 sc1)
    }
    __syncthreads();
  }
  if (tid < 256) cws[gb * U_DIM + u] = c_reg;
}

extern "C" void kernel_launch(void* const* d_in, const int* in_sizes, int n_in,
                              void* d_out, int out_size, void* d_ws, size_t ws_size,
                              hipStream_t stream) {
  const float* x = (const float*)d_in[0];
  const float* W = (const float*)d_in[1];
  const float* Wr = (const float*)d_in[2];
  const float* bias = (const float*)d_in[3];
  float* out = (float*)d_out;

  const size_t ZXC_B = (size_t)CH * B_DIM * G_DIM * 4;      // 67,633,152
  const size_t XT_B = (size_t)T_DIM * B_DIM * K_DIM * 2;    // 67,108,864
  const size_t WT_B = (size_t)G_DIM * K_DIM * 2;            // 8,454,144
  const size_t HB_B = (size_t)2 * B_DIM * U_DIM * 2;        // 262,144
  const size_t CW_B = (size_t)B_DIM * U_DIM * 4;            // 262,144
  const size_t BP_B = 17408;
  const size_t FL_B = 4096;
  const size_t NEED_OLD = ZXC_B + 2 * WT_B + HB_B + CW_B + FL_B;          // ~85.1 MB
  const size_t NEED_NEW = NEED_OLD + XT_B + BP_B;                          // ~152.2 MB
  if (ws_size < NEED_OLD) return;
  const bool fast = (ws_size >= NEED_NEW);

  char* ws = (char*)d_ws;
  float* Zxc = (float*)ws;                       ws += ZXC_B;
  __bf16* xt = nullptr; float* biasP = nullptr;
  if (fast) { xt = (__bf16*)ws;                  ws += XT_B; }
  __bf16* Wt = (__bf16*)ws;                      ws += WT_B;
  __bf16* Wrt = (__bf16*)ws;                     ws += WT_B;
  __bf16* hb = (__bf16*)ws;                      ws += HB_B;
  float* cws = (float*)ws;                       ws += CW_B;
  if (fast) { biasP = (float*)ws;                ws += BP_B; }
  unsigned* flags = (unsigned*)ws;

  hipMemsetAsync(hb, 0, HB_B, stream);
  hipMemsetAsync(cws, 0, CW_B, stream);
  hipMemsetAsync(flags, 0, FL_B, stream);
  transpose_perm_kernel<<<1032, 256, 0, stream>>>(W, Wt);
  transpose_perm_kernel<<<1032, 256, 0, stream>>>(Wr, Wrt);
  if (fast) {
    biasperm_kernel<<<17, 256, 0, stream>>>(bias, biasP);
    xcast_kernel<<<16384, 256, 0, stream>>>(x, xt);
  }

  for (int c = 0; c < NCHUNK; ++c) {
    int t0 = c * CH;
    if (fast) {
      const __bf16* xtc = xt + (size_t)t0 * B_DIM * K_DIM;
      gemm1f_kernel<<<dim3(32, 33), 512, 0, stream>>>(xtc, Wt, biasP, Zxc);
    } else {
      gemm1_kernel<<<dim3(64, 65), 256, 0, stream>>>(x, Wt, bias, Zxc, t0);
    }
    recur_kernel<<<NBLK, 384, 0, stream>>>(Zxc, Wrt, hb, cws, flags, out, t0);
  }
}